// Round 15
// baseline (305.269 us; speedup 1.0000x reference)
//
#include <hip/hip_runtime.h>

#define NNODES 20000
#define BATCH  2
#define FEAT   256
#define OOUT   64
#define PBLK2  400        // pool stage-1 blocks (100 flattened rows each)
#define MROWS  40000
#define NPB    20096      // padded nodes per batch (157*128)
#define H8ROWS 40192      // 2*NPB interleaved rows (n*2+b)
#define NCHUNK 20

typedef short  bhalf8 __attribute__((ext_vector_type(8)));
typedef float  floatx4 __attribute__((ext_vector_type(4)));
typedef float  floatx2 __attribute__((ext_vector_type(2)));

__device__ __forceinline__ float bf2f(unsigned short u) {
  return __uint_as_float(((unsigned int)u) << 16);
}
__device__ __forceinline__ unsigned short f2bf(float f) {  // RNE
  unsigned int u = __float_as_uint(f);
  return (unsigned short)((u + 0x7fffu + ((u >> 16) & 1u)) >> 16);
}
__device__ __forceinline__ unsigned int pack4_fp8(float a, float b, float c, float d) {
  int p = __builtin_amdgcn_cvt_pk_fp8_f32(a, b, 0, false);
  p = __builtin_amdgcn_cvt_pk_fp8_f32(c, d, p, true);
  return (unsigned int)p;
}

// ---------- prep: zero cnt/fill/chunkOff + wprep (both W) + detect edge dtype; grid=512 ----------
__global__ __launch_bounds__(256) void prep_kernel(const float* __restrict__ W1,
                                                   const float* __restrict__ W2,
                                                   unsigned short* __restrict__ w1hi,
                                                   unsigned short* __restrict__ w1lo,
                                                   unsigned short* __restrict__ w2hi,
                                                   unsigned short* __restrict__ w2lo,
                                                   const int* __restrict__ raw, int E,
                                                   int* __restrict__ flag,
                                                   int* __restrict__ cnt,
                                                   int* __restrict__ fill,
                                                   int* __restrict__ chunkOff) {
  int bid = blockIdx.x, tid = threadIdx.x;
  int idx = bid * 256 + tid;                 // [0, 131072)
  int which = idx >> 16, loc = idx & 65535;
  const float* W = which ? W2 : W1;
  unsigned short* Whi = which ? w2hi : w1hi;
  unsigned short* Wlo = which ? w2lo : w1lo;
  int k = loc >> 8, n = loc & 255;
  float w = W[loc];
  unsigned short hi = f2bf(w);
  unsigned short lo = f2bf(w - bf2f(hi));
  int g = n >> 4, ln = n & 15;
  int ks = k >> 5, ch = (k >> 3) & 3, j = k & 7;
  int addr = ((ks * 16 + g) * 64 + ch * 16 + ln) * 8 + j;
  Whi[addr] = hi;
  Wlo[addr] = lo;
  if (idx < NNODES) { cnt[idx] = 0; fill[idx] = 0; }
  if (idx < NCHUNK) chunkOff[idx] = 0;
  if (bid == 511) {
    __shared__ int any;
    if (tid == 0) any = 0;
    __syncthreads();
    int nchk = E < 2048 ? E : 2048;
    for (int i = tid; i < nchk; i += 256)
      if (raw[2 * i + 1] != 0) any = 1;      // int64 high words are 0
    __syncthreads();
    if (tid == 0) *flag = any;               // 1 => int32 layout
  }
}

// ---------- degree count straight from eraw ----------
__global__ void count_kernel(const int* __restrict__ raw, const int* __restrict__ flag,
                             int* __restrict__ cnt, int E) {
  int e = blockIdx.x * blockDim.x + threadIdx.x;
  if (e >= E) return;
  int d = (*flag) ? raw[E + e] : raw[2 * (E + e)];
  atomicAdd(&cnt[d], 1);
}

// ---------- parallel scan: 20 blocks, local exclusive scan + dinv; chunk totals via int atomics ----------
__global__ __launch_bounds__(256) void scan_a_kernel(const int* __restrict__ cnt,
                                                     int* __restrict__ row_start,
                                                     float* __restrict__ dinv,
                                                     int* __restrict__ chunkOff) {
  int c = blockIdx.x, tid = threadIdx.x;
  int base = c * 1024 + tid * 4;
  int v[4]; int tsum = 0;
#pragma unroll
  for (int j = 0; j < 4; ++j) {
    v[j] = (base + j < NNODES) ? cnt[base + j] : 0;
    tsum += v[j];
  }
  int lane = tid & 63, wv = tid >> 6;
  int x = tsum;
#pragma unroll
  for (int off = 1; off < 64; off <<= 1) {
    int t = __shfl_up(x, off);
    if (lane >= off) x += t;
  }
  __shared__ int wsum[4];
  if (lane == 63) wsum[wv] = x;
  __syncthreads();
  int woff = 0;
  for (int w = 0; w < wv; ++w) woff += wsum[w];
  int run = woff + x - tsum;                 // exclusive prefix (local to chunk)
#pragma unroll
  for (int j = 0; j < 4; ++j) {
    if (base + j <= NNODES) row_start[base + j] = run;   // local-exclusive; global = +chunkOff
    if (base + j < NNODES) dinv[base + j] = 1.0f / sqrtf((float)(v[j] + 1));
    run += v[j];
  }
  if (tid == 0) {
    int T = wsum[0] + wsum[1] + wsum[2] + wsum[3];
    for (int c2 = c + 1; c2 < NCHUNK; ++c2) atomicAdd(&chunkOff[c2], T);  // int: exact, order-free
  }
}

// ---------- scatter straight from eraw ----------
__global__ void scatter_kernel(const int* __restrict__ raw, const int* __restrict__ flag,
                               const int* __restrict__ row_start, const int* __restrict__ chunkOff,
                               int* __restrict__ fill, const float* __restrict__ dinv,
                               int* __restrict__ csr_src, float* __restrict__ csr_norm, int E) {
  int e = blockIdx.x * blockDim.x + threadIdx.x;
  if (e >= E) return;
  int s, d;
  if (*flag) { s = raw[e];     d = raw[E + e]; }
  else       { s = raw[2 * e]; d = raw[2 * (E + e)]; }
  int p = row_start[d] + chunkOff[d >> 10] + atomicAdd(&fill[d], 1);
  csr_src[p] = s;
  csr_norm[p] = dinv[s] * dinv[d];
}

// ---------- MFMA GEMM: 32KiB dbuf LDS; XCD-paired swizzle (halves of a tile 8 bids apart) ----------
template <int AFP32>
__global__ __launch_bounds__(256) void gemm_mfma(const void* __restrict__ Av,
                                                 const unsigned short* __restrict__ Whi,
                                                 const unsigned short* __restrict__ Wlo,
                                                 unsigned int* __restrict__ C) {
  int bid = blockIdx.x;
  int tile = (bid >> 4) * 8 + (bid & 7);
  int half = (bid >> 3) & 1;
  if (tile >= 314) return;
  __shared__ unsigned short lds[2][8192];
  int b = tile >= 157 ? 1 : 0;
  int nbase = (tile - b * 157) * 128;
  int tid = threadIdx.x, lane = tid & 63, wv = tid >> 6;
  int kc = (lane >> 4) * 8;

  const float* Af          = (const float*)Av;
  const unsigned short* Ab = (const unsigned short*)Av;

  int nn[2], mr[2];
#pragma unroll
  for (int t = 0; t < 2; ++t) {
    int nl = nbase + wv * 32 + t * 16 + (lane & 15);
    nn[t] = nl;
    int ncl = nl > NNODES - 1 ? NNODES - 1 : nl;
    mr[t] = b * NNODES + ncl;
  }

  floatx4 acc[2][8];
#pragma unroll
  for (int t = 0; t < 2; ++t)
#pragma unroll
    for (int g = 0; g < 8; ++g) acc[t][g] = (floatx4)(0.0f);

  bhalf8 st[4];
  auto stage_load = [&](int ks) {
#pragma unroll
    for (int i2 = 0; i2 < 4; ++i2) {
      int u = i2 * 256 + tid;
      int hl = u >> 9, g = (u >> 6) & 7, l = u & 63;
      const unsigned short* Wp = hl ? Wlo : Whi;
      st[i2] = *(const bhalf8*)&Wp[((size_t)(ks * 16 + half * 8 + g) * 64 + l) * 8];
    }
  };
  auto stage_write = [&](int buf) {
#pragma unroll
    for (int i2 = 0; i2 < 4; ++i2) {
      int u = i2 * 256 + tid;
      *(bhalf8*)&lds[buf][(size_t)u * 8] = st[i2];
    }
  };
  auto load_a = [&](int ks, bhalf8 (&a)[2]) {
#pragma unroll
    for (int t = 0; t < 2; ++t) {
      if (AFP32) {
        const float* p = &Af[(size_t)mr[t] * FEAT + ks * 32 + kc];
        float4 u = *(const float4*)p;
        float4 v = *(const float4*)(p + 4);
        a[t][0] = (short)f2bf(u.x); a[t][1] = (short)f2bf(u.y);
        a[t][2] = (short)f2bf(u.z); a[t][3] = (short)f2bf(u.w);
        a[t][4] = (short)f2bf(v.x); a[t][5] = (short)f2bf(v.y);
        a[t][6] = (short)f2bf(v.z); a[t][7] = (short)f2bf(v.w);
      } else {
        a[t] = *(const bhalf8*)&Ab[(size_t)mr[t] * FEAT + ks * 32 + kc];
      }
    }
  };
  auto step = [&](int buf, bhalf8 (&a)[2]) {
#pragma unroll
    for (int g = 0; g < 8; ++g) {
      bhalf8 bh = *(const bhalf8*)&lds[buf][((size_t)g * 64 + lane) * 8];
      bhalf8 bl = *(const bhalf8*)&lds[buf][((size_t)(512 + g * 64) + lane) * 8];
#pragma unroll
      for (int t = 0; t < 2; ++t)
        acc[t][g] = __builtin_amdgcn_mfma_f32_16x16x32_bf16(bh, a[t], acc[t][g], 0, 0, 0);
#pragma unroll
      for (int t = 0; t < 2; ++t)
        acc[t][g] = __builtin_amdgcn_mfma_f32_16x16x32_bf16(bl, a[t], acc[t][g], 0, 0, 0);
    }
  };

  stage_load(0);
  stage_write(0);
  __syncthreads();
  bhalf8 aC[2];
  load_a(0, aC);
  int cur = 0;
#pragma unroll
  for (int ks = 0; ks < 8; ++ks) {
    bhalf8 aN[2];
    if (ks < 7) {
      stage_load(ks + 1);
      load_a(ks + 1, aN);
    }
    step(cur, aC);
    if (ks < 7) {
      stage_write(cur ^ 1);
      __syncthreads();
      aC[0] = aN[0]; aC[1] = aN[1];
    }
    cur ^= 1;
  }

  int nc = (lane >> 4) * 4;
#pragma unroll
  for (int t = 0; t < 2; ++t) {
    size_t r = (size_t)nn[t] * 2 + b;
#pragma unroll
    for (int g = 0; g < 8; ++g) {
      int col = (half * 8 + g) * 16 + nc;
      C[r * 64 + (col >> 2)] =
          pack4_fp8(acc[t][g][0], acc[t][g][1], acc[t][g][2], acc[t][g][3]);
    }
  }
}

// ---------- aggregation, L2-sliced: grid = 4*NNODES, slice-major block order ----------
// slice s = bid/NNODES = (h<<1)|b selects a 2.57MB (batch, feat-half) slice of h8 that fits
// each XCD's 4MB L2; dispatch order keeps the ~2K concurrent blocks within one slice, so
// gathers are L2-resident after first touch (same bytes/requests as 512B rows, higher hit rate).
// 128 thr: slot = (wave<<3)|(lane>>3) in [0,16) handles edges (i-s0)%16==slot;
// cl = lane&7 -> one uint4 (16 fp8 feats) of the 128B slice row.
__global__ __launch_bounds__(128) void agg_kernel(const uint4* __restrict__ h8,
                                                  const int* __restrict__ row_start,
                                                  const int* __restrict__ chunkOff,
                                                  const int* __restrict__ csr_src,
                                                  const float* __restrict__ csr_norm,
                                                  const float* __restrict__ dinv,
                                                  const float* __restrict__ bias,
                                                  unsigned short* __restrict__ out) {
  int bid = blockIdx.x;
  int s = bid / NNODES;                // slice 0..3 (slice-major: blocks of one slice contiguous)
  int n = bid - s * NNODES;
  int b = s & 1, h = s >> 1;           // batch, feat-half
  int tid = threadIdx.x;
  int wave = tid >> 6, lane = tid & 63;
  int slot = (wave << 3) | (lane >> 3);   // edge slot 0..15
  int cl = lane & 7;                      // uint4 index within the 128B slice row
  int ubase = b * 16 + h * 8 + cl;        // uint4 offset within a 512B node row

  float a[16];
#pragma unroll
  for (int j = 0; j < 16; ++j) a[j] = 0.0f;

  auto dec_fma = [&](uint4 m, float w) {
    unsigned int mm[4] = {m.x, m.y, m.z, m.w};
#pragma unroll
    for (int j = 0; j < 4; ++j) {
      floatx2 lo = __builtin_amdgcn_cvt_pk_f32_fp8((int)mm[j], false);
      floatx2 hi = __builtin_amdgcn_cvt_pk_f32_fp8((int)mm[j], true);
      a[j * 4 + 0] = fmaf(w, lo[0], a[j * 4 + 0]);
      a[j * 4 + 1] = fmaf(w, lo[1], a[j * 4 + 1]);
      a[j * 4 + 2] = fmaf(w, hi[0], a[j * 4 + 2]);
      a[j * 4 + 3] = fmaf(w, hi[1], a[j * 4 + 3]);
    }
  };

  float di = dinv[n];
  if (slot == 0) dec_fma(h8[(size_t)n * 32 + ubase], di * di);   // self term

  int s0 = row_start[n] + chunkOff[n >> 10];
  int s1 = row_start[n + 1] + chunkOff[(n + 1) >> 10];
  for (int i = s0 + slot; i < s1; i += 16) {   // 16 gathers in flight per block
    int sa = csr_src[i];
    float wa = csr_norm[i];
    dec_fma(h8[(size_t)sa * 32 + ubase], wa);
  }

  // combine 16 slots: lanes with equal (lane&7) form xor-groups over bits 3,4 then cross-wave
#pragma unroll
  for (int j = 0; j < 16; ++j) {
    a[j] += __shfl_xor(a[j], 8);
    a[j] += __shfl_xor(a[j], 16);
    a[j] += __shfl_xor(a[j], 32);
  }
  __shared__ float red[8][17];
  if (wave == 1 && lane < 8) {
#pragma unroll
    for (int j = 0; j < 16; ++j) red[lane][j] = a[j];
  }
  __syncthreads();
  if (wave == 0 && lane < 8) {
    int c = h * 128 + cl * 16;          // feature base (16 feats per lane)
#pragma unroll
    for (int j = 0; j < 16; ++j) a[j] += red[lane][j];
    unsigned short o[16];
#pragma unroll
    for (int j = 0; j < 16; ++j)
      o[j] = f2bf(fmaxf(a[j] + bias[c + j], 0.0f));
    unsigned short* dst = &out[((size_t)b * NNODES + n) * FEAT + c];
    *(uint4*)dst = *(uint4*)&o[0];
    *(uint4*)(dst + 8) = *(uint4*)&o[8];
  }
}

// ---------- pooling stage 1: VECTORIZED (uint4 = 8 bf16 per lane), 400 blocks x 100 rows ----------
__global__ __launch_bounds__(256) void pool_partial(const uint4* __restrict__ h2u,
                                                    float* __restrict__ partials) {
  int blk = blockIdx.x;
  int tid = threadIdx.x;
  int rg = tid >> 5, cl = tid & 31;
  int rend = blk * 100 + 100;
  float acc[8];
#pragma unroll
  for (int j = 0; j < 8; ++j) acc[j] = 0.0f;
  for (int r = blk * 100 + rg; r < rend; r += 8) {
    uint4 m = h2u[(size_t)r * 32 + cl];
    unsigned int mm[4] = {m.x, m.y, m.z, m.w};
#pragma unroll
    for (int j = 0; j < 4; ++j) {
      acc[2 * j + 0] += bf2f((unsigned short)(mm[j] & 0xffffu));
      acc[2 * j + 1] += bf2f((unsigned short)(mm[j] >> 16));
    }
  }
  __shared__ float red[8][256];
#pragma unroll
  for (int j = 0; j < 8; ++j) red[rg][cl * 8 + j] = acc[j];
  __syncthreads();
  float s = red[0][tid] + red[1][tid] + red[2][tid] + red[3][tid]
          + red[4][tid] + red[5][tid] + red[6][tid] + red[7][tid];
  partials[(size_t)blk * 256 + tid] = s;
}

// ---------- pooling stage 2 + FC (400 KB read, single block) ----------
__global__ __launch_bounds__(256) void pool_fc(const float* __restrict__ partials,
                                               const float* __restrict__ Wfc,
                                               const float* __restrict__ bfc,
                                               float* __restrict__ out) {
  __shared__ float pooled[BATCH][FEAT];
  int t = threadIdx.x;
  float s0 = 0.f, s1 = 0.f;
  for (int p = 0; p < PBLK2 / 2; ++p) {
    s0 += partials[(size_t)p * 256 + t];
    s1 += partials[(size_t)(PBLK2 / 2 + p) * 256 + t];
  }
  pooled[0][t] = s0 / (float)NNODES;
  pooled[1][t] = s1 / (float)NNODES;
  __syncthreads();
  if (t < BATCH * OOUT) {
    int b = t >> 6, o = t & 63;
    float acc = bfc[o];
    for (int c2 = 0; c2 < FEAT; ++c2)
      acc = fmaf(pooled[b][c2], Wfc[c2 * OOUT + o], acc);
    out[b * OOUT + o] = acc;
  }
}

extern "C" void kernel_launch(void* const* d_in, const int* in_sizes, int n_in,
                              void* d_out, int out_size, void* d_ws, size_t ws_size,
                              hipStream_t stream) {
  const float* x    = (const float*)d_in[0];
  const float* W1   = (const float*)d_in[1];
  const float* b1   = (const float*)d_in[2];
  const float* W2   = (const float*)d_in[3];
  const float* b2   = (const float*)d_in[4];
  const float* Wfc  = (const float*)d_in[5];
  const float* bfc  = (const float*)d_in[6];
  const int*   eraw = (const int*)d_in[7];
  int E = in_sizes[7] / 2;
  float* out = (float*)d_out;

  char* ws = (char*)d_ws;
  size_t off = 0;
  auto alloc = [&](size_t elems4B) -> void* {
    void* p = ws + off * 4;
    off += (elems4B + 3) & ~(size_t)3;
    return p;
  };
  int*   flag      = (int*)alloc(4);
  int*   cnt       = (int*)alloc(NNODES);
  float* dinv      = (float*)alloc(NNODES);
  int*   row_start = (int*)alloc(NNODES + 1);
  int*   fill      = (int*)alloc(NNODES);
  int*   chunkOff  = (int*)alloc(NCHUNK + 4);
  int*   csr_src   = (int*)alloc(E);
  float* csr_norm  = (float*)alloc(E);
  unsigned short* w1hi = (unsigned short*)alloc(65536 / 2);
  unsigned short* w1lo = (unsigned short*)alloc(65536 / 2);
  unsigned short* w2hi = (unsigned short*)alloc(65536 / 2);
  unsigned short* w2lo = (unsigned short*)alloc(65536 / 2);
  unsigned int*   h8   = (unsigned int*)alloc((size_t)H8ROWS * 64);
  unsigned short* a1   = (unsigned short*)alloc((size_t)MROWS * FEAT / 2);
  float* partials  = (float*)alloc((size_t)PBLK2 * 256);

  int eg = (E + 255) / 256;
  prep_kernel<<<512, 256, 0, stream>>>(W1, W2, w1hi, w1lo, w2hi, w2lo, eraw, E, flag,
                                       cnt, fill, chunkOff);
  count_kernel<<<eg, 256, 0, stream>>>(eraw, flag, cnt, E);
  scan_a_kernel<<<NCHUNK, 256, 0, stream>>>(cnt, row_start, dinv, chunkOff);
  scatter_kernel<<<eg, 256, 0, stream>>>(eraw, flag, row_start, chunkOff, fill, dinv,
                                         csr_src, csr_norm, E);

  gemm_mfma<1><<<640, 256, 0, stream>>>(x, w1hi, w1lo, h8);
  agg_kernel<<<4 * NNODES, 128, 0, stream>>>((const uint4*)h8, row_start, chunkOff,
                                             csr_src, csr_norm, dinv, b1, a1);
  gemm_mfma<0><<<640, 256, 0, stream>>>(a1, w2hi, w2lo, h8);
  agg_kernel<<<4 * NNODES, 128, 0, stream>>>((const uint4*)h8, row_start, chunkOff,
                                             csr_src, csr_norm, dinv, b2, a1);
  pool_partial<<<PBLK2, 256, 0, stream>>>((const uint4*)a1, partials);
  pool_fc<<<1, 256, 0, stream>>>(partials, Wfc, bfc, out);
}

// Round 16
// 183.269 us; speedup vs baseline: 1.6657x; 1.6657x over previous
//
#include <hip/hip_runtime.h>

#define NNODES 20000
#define BATCH  2
#define FEAT   256
#define OOUT   64
#define PBLK2  400        // pool stage-1 blocks (100 flattened rows each)
#define MROWS  40000
#define NPB    20096      // padded nodes per batch (157*128)
#define H8ROWS 40192      // 2*NPB interleaved rows (n*2+b)
#define NCHUNK 20

typedef short  bhalf8 __attribute__((ext_vector_type(8)));
typedef float  floatx4 __attribute__((ext_vector_type(4)));
typedef float  floatx2 __attribute__((ext_vector_type(2)));

__device__ __forceinline__ float bf2f(unsigned short u) {
  return __uint_as_float(((unsigned int)u) << 16);
}
__device__ __forceinline__ unsigned short f2bf(float f) {  // RNE
  unsigned int u = __float_as_uint(f);
  return (unsigned short)((u + 0x7fffu + ((u >> 16) & 1u)) >> 16);
}
__device__ __forceinline__ unsigned int pack4_fp8(float a, float b, float c, float d) {
  int p = __builtin_amdgcn_cvt_pk_fp8_f32(a, b, 0, false);
  p = __builtin_amdgcn_cvt_pk_fp8_f32(c, d, p, true);
  return (unsigned int)p;
}

// ---------- prep: zero cnt/fill/chunkOff + wprep (both W) + detect edge dtype; grid=512 ----------
__global__ __launch_bounds__(256) void prep_kernel(const float* __restrict__ W1,
                                                   const float* __restrict__ W2,
                                                   unsigned short* __restrict__ w1hi,
                                                   unsigned short* __restrict__ w1lo,
                                                   unsigned short* __restrict__ w2hi,
                                                   unsigned short* __restrict__ w2lo,
                                                   const int* __restrict__ raw, int E,
                                                   int* __restrict__ flag,
                                                   int* __restrict__ cnt,
                                                   int* __restrict__ fill,
                                                   int* __restrict__ chunkOff) {
  int bid = blockIdx.x, tid = threadIdx.x;
  int idx = bid * 256 + tid;                 // [0, 131072)
  int which = idx >> 16, loc = idx & 65535;
  const float* W = which ? W2 : W1;
  unsigned short* Whi = which ? w2hi : w1hi;
  unsigned short* Wlo = which ? w2lo : w1lo;
  int k = loc >> 8, n = loc & 255;
  float w = W[loc];
  unsigned short hi = f2bf(w);
  unsigned short lo = f2bf(w - bf2f(hi));
  int g = n >> 4, ln = n & 15;
  int ks = k >> 5, ch = (k >> 3) & 3, j = k & 7;
  int addr = ((ks * 16 + g) * 64 + ch * 16 + ln) * 8 + j;
  Whi[addr] = hi;
  Wlo[addr] = lo;
  if (idx < NNODES) { cnt[idx] = 0; fill[idx] = 0; }
  if (idx < NCHUNK) chunkOff[idx] = 0;
  if (bid == 511) {
    __shared__ int any;
    if (tid == 0) any = 0;
    __syncthreads();
    int nchk = E < 2048 ? E : 2048;
    for (int i = tid; i < nchk; i += 256)
      if (raw[2 * i + 1] != 0) any = 1;      // int64 high words are 0
    __syncthreads();
    if (tid == 0) *flag = any;               // 1 => int32 layout
  }
}

// ---------- degree count straight from eraw ----------
__global__ void count_kernel(const int* __restrict__ raw, const int* __restrict__ flag,
                             int* __restrict__ cnt, int E) {
  int e = blockIdx.x * blockDim.x + threadIdx.x;
  if (e >= E) return;
  int d = (*flag) ? raw[E + e] : raw[2 * (E + e)];
  atomicAdd(&cnt[d], 1);
}

// ---------- parallel scan: 20 blocks, local exclusive scan + dinv; chunk totals via int atomics ----------
__global__ __launch_bounds__(256) void scan_a_kernel(const int* __restrict__ cnt,
                                                     int* __restrict__ row_start,
                                                     float* __restrict__ dinv,
                                                     int* __restrict__ chunkOff) {
  int c = blockIdx.x, tid = threadIdx.x;
  int base = c * 1024 + tid * 4;
  int v[4]; int tsum = 0;
#pragma unroll
  for (int j = 0; j < 4; ++j) {
    v[j] = (base + j < NNODES) ? cnt[base + j] : 0;
    tsum += v[j];
  }
  int lane = tid & 63, wv = tid >> 6;
  int x = tsum;
#pragma unroll
  for (int off = 1; off < 64; off <<= 1) {
    int t = __shfl_up(x, off);
    if (lane >= off) x += t;
  }
  __shared__ int wsum[4];
  if (lane == 63) wsum[wv] = x;
  __syncthreads();
  int woff = 0;
  for (int w = 0; w < wv; ++w) woff += wsum[w];
  int run = woff + x - tsum;                 // exclusive prefix (local to chunk)
#pragma unroll
  for (int j = 0; j < 4; ++j) {
    if (base + j <= NNODES) row_start[base + j] = run;   // local-exclusive; global = +chunkOff
    if (base + j < NNODES) dinv[base + j] = 1.0f / sqrtf((float)(v[j] + 1));
    run += v[j];
  }
  if (tid == 0) {
    int T = wsum[0] + wsum[1] + wsum[2] + wsum[3];
    for (int c2 = c + 1; c2 < NCHUNK; ++c2) atomicAdd(&chunkOff[c2], T);  // int: exact, order-free
  }
}

// ---------- scatter straight from eraw ----------
__global__ void scatter_kernel(const int* __restrict__ raw, const int* __restrict__ flag,
                               const int* __restrict__ row_start, const int* __restrict__ chunkOff,
                               int* __restrict__ fill, const float* __restrict__ dinv,
                               int* __restrict__ csr_src, float* __restrict__ csr_norm, int E) {
  int e = blockIdx.x * blockDim.x + threadIdx.x;
  if (e >= E) return;
  int s, d;
  if (*flag) { s = raw[e];     d = raw[E + e]; }
  else       { s = raw[2 * e]; d = raw[2 * (E + e)]; }
  int p = row_start[d] + chunkOff[d >> 10] + atomicAdd(&fill[d], 1);
  csr_src[p] = s;
  csr_norm[p] = dinv[s] * dinv[d];
}

// ---------- MFMA GEMM: 32KiB dbuf LDS; XCD-paired swizzle (halves of a tile 8 bids apart) ----------
template <int AFP32>
__global__ __launch_bounds__(256) void gemm_mfma(const void* __restrict__ Av,
                                                 const unsigned short* __restrict__ Whi,
                                                 const unsigned short* __restrict__ Wlo,
                                                 unsigned int* __restrict__ C) {
  int bid = blockIdx.x;
  int tile = (bid >> 4) * 8 + (bid & 7);
  int half = (bid >> 3) & 1;
  if (tile >= 314) return;
  __shared__ unsigned short lds[2][8192];
  int b = tile >= 157 ? 1 : 0;
  int nbase = (tile - b * 157) * 128;
  int tid = threadIdx.x, lane = tid & 63, wv = tid >> 6;
  int kc = (lane >> 4) * 8;

  const float* Af          = (const float*)Av;
  const unsigned short* Ab = (const unsigned short*)Av;

  int nn[2], mr[2];
#pragma unroll
  for (int t = 0; t < 2; ++t) {
    int nl = nbase + wv * 32 + t * 16 + (lane & 15);
    nn[t] = nl;
    int ncl = nl > NNODES - 1 ? NNODES - 1 : nl;
    mr[t] = b * NNODES + ncl;
  }

  floatx4 acc[2][8];
#pragma unroll
  for (int t = 0; t < 2; ++t)
#pragma unroll
    for (int g = 0; g < 8; ++g) acc[t][g] = (floatx4)(0.0f);

  bhalf8 st[4];
  auto stage_load = [&](int ks) {
#pragma unroll
    for (int i2 = 0; i2 < 4; ++i2) {
      int u = i2 * 256 + tid;
      int hl = u >> 9, g = (u >> 6) & 7, l = u & 63;
      const unsigned short* Wp = hl ? Wlo : Whi;
      st[i2] = *(const bhalf8*)&Wp[((size_t)(ks * 16 + half * 8 + g) * 64 + l) * 8];
    }
  };
  auto stage_write = [&](int buf) {
#pragma unroll
    for (int i2 = 0; i2 < 4; ++i2) {
      int u = i2 * 256 + tid;
      *(bhalf8*)&lds[buf][(size_t)u * 8] = st[i2];
    }
  };
  auto load_a = [&](int ks, bhalf8 (&a)[2]) {
#pragma unroll
    for (int t = 0; t < 2; ++t) {
      if (AFP32) {
        const float* p = &Af[(size_t)mr[t] * FEAT + ks * 32 + kc];
        float4 u = *(const float4*)p;
        float4 v = *(const float4*)(p + 4);
        a[t][0] = (short)f2bf(u.x); a[t][1] = (short)f2bf(u.y);
        a[t][2] = (short)f2bf(u.z); a[t][3] = (short)f2bf(u.w);
        a[t][4] = (short)f2bf(v.x); a[t][5] = (short)f2bf(v.y);
        a[t][6] = (short)f2bf(v.z); a[t][7] = (short)f2bf(v.w);
      } else {
        a[t] = *(const bhalf8*)&Ab[(size_t)mr[t] * FEAT + ks * 32 + kc];
      }
    }
  };
  auto step = [&](int buf, bhalf8 (&a)[2]) {
#pragma unroll
    for (int g = 0; g < 8; ++g) {
      bhalf8 bh = *(const bhalf8*)&lds[buf][((size_t)g * 64 + lane) * 8];
      bhalf8 bl = *(const bhalf8*)&lds[buf][((size_t)(512 + g * 64) + lane) * 8];
#pragma unroll
      for (int t = 0; t < 2; ++t)
        acc[t][g] = __builtin_amdgcn_mfma_f32_16x16x32_bf16(bh, a[t], acc[t][g], 0, 0, 0);
#pragma unroll
      for (int t = 0; t < 2; ++t)
        acc[t][g] = __builtin_amdgcn_mfma_f32_16x16x32_bf16(bl, a[t], acc[t][g], 0, 0, 0);
    }
  };

  stage_load(0);
  stage_write(0);
  __syncthreads();
  bhalf8 aC[2];
  load_a(0, aC);
  int cur = 0;
#pragma unroll
  for (int ks = 0; ks < 8; ++ks) {
    bhalf8 aN[2];
    if (ks < 7) {
      stage_load(ks + 1);
      load_a(ks + 1, aN);
    }
    step(cur, aC);
    if (ks < 7) {
      stage_write(cur ^ 1);
      __syncthreads();
      aC[0] = aN[0]; aC[1] = aN[1];
    }
    cur ^= 1;
  }

  int nc = (lane >> 4) * 4;
#pragma unroll
  for (int t = 0; t < 2; ++t) {
    size_t r = (size_t)nn[t] * 2 + b;
#pragma unroll
    for (int g = 0; g < 8; ++g) {
      int col = (half * 8 + g) * 16 + nc;
      C[r * 64 + (col >> 2)] =
          pack4_fp8(acc[t][g][0], acc[t][g][1], acc[t][g][2], acc[t][g][3]);
    }
  }
}

// ---------- aggregation: one node per block; h8 rows are 512B (n*2+b interleaved) ----------
// 128 thr: slot q = (wave<<1)|(lane>>5) handles edges (i-s0)%4==q; cl = lane&31 spans the
// 512B row (cl<16: batch0 feats, cl>=16: batch1). 3-deep edge pipeline (12 gathers in
// flight per wave-pair); per-slot accumulation order identical to 2-deep (bit-exact).
__global__ __launch_bounds__(128) void agg_kernel(const uint4* __restrict__ h8,
                                                  const int* __restrict__ row_start,
                                                  const int* __restrict__ chunkOff,
                                                  const int* __restrict__ csr_src,
                                                  const float* __restrict__ csr_norm,
                                                  const float* __restrict__ dinv,
                                                  const float* __restrict__ bias,
                                                  unsigned short* __restrict__ out) {
  int n = blockIdx.x;
  int tid = threadIdx.x;
  int wave = tid >> 6, lane = tid & 63;
  int q = (wave << 1) | (lane >> 5);   // edge slot 0..3
  int cl = lane & 31;                  // uint4 index within 512B row

  float a[16];
#pragma unroll
  for (int j = 0; j < 16; ++j) a[j] = 0.0f;

  auto dec_fma = [&](uint4 m, float w) {
    unsigned int mm[4] = {m.x, m.y, m.z, m.w};
#pragma unroll
    for (int j = 0; j < 4; ++j) {
      floatx2 lo = __builtin_amdgcn_cvt_pk_f32_fp8((int)mm[j], false);
      floatx2 hi = __builtin_amdgcn_cvt_pk_f32_fp8((int)mm[j], true);
      a[j * 4 + 0] = fmaf(w, lo[0], a[j * 4 + 0]);
      a[j * 4 + 1] = fmaf(w, lo[1], a[j * 4 + 1]);
      a[j * 4 + 2] = fmaf(w, hi[0], a[j * 4 + 2]);
      a[j * 4 + 3] = fmaf(w, hi[1], a[j * 4 + 3]);
    }
  };

  float di = dinv[n];
  if (q == 0) dec_fma(h8[(size_t)n * 32 + cl], di * di);   // self term, both batches

  int s0 = row_start[n] + chunkOff[n >> 10];
  int s1 = row_start[n + 1] + chunkOff[(n + 1) >> 10];
  int i = s0 + q;
  // 3-deep: at mean degree 16 (4 edges/slot) this path executes (q+8 < 16 for q<=3),
  // consuming 3 edges, leaving 1 for the tail loop. 12 x 512B gathers in flight/block.
  for (; i + 8 < s1; i += 12) {
    int sa = csr_src[i], sb = csr_src[i + 4], sc = csr_src[i + 8];
    float wa = csr_norm[i], wb = csr_norm[i + 4], wc = csr_norm[i + 8];
    uint4 ma = h8[(size_t)sa * 32 + cl];
    uint4 mb = h8[(size_t)sb * 32 + cl];
    uint4 mc = h8[(size_t)sc * 32 + cl];
    dec_fma(ma, wa);
    dec_fma(mb, wb);
    dec_fma(mc, wc);
  }
  for (; i < s1; i += 4)
    dec_fma(h8[(size_t)csr_src[i] * 32 + cl], csr_norm[i]);

  // combine slot pairs within each wave
#pragma unroll
  for (int j = 0; j < 16; ++j) a[j] += __shfl_xor(a[j], 32);

  // cross-wave combine via LDS (padded stride 17: conflict-free)
  __shared__ float red[32][17];
  if (wave == 1 && lane < 32) {
#pragma unroll
    for (int j = 0; j < 16; ++j) red[lane][j] = a[j];
  }
  __syncthreads();
  if (wave == 0 && lane < 32) {
    int b = cl >> 4;                    // batch
    int c = (cl & 15) * 16;             // feature base
#pragma unroll
    for (int j = 0; j < 16; ++j) a[j] += red[lane][j];
    unsigned short o[16];
#pragma unroll
    for (int j = 0; j < 16; ++j)
      o[j] = f2bf(fmaxf(a[j] + bias[c + j], 0.0f));
    unsigned short* dst = &out[((size_t)b * NNODES + n) * FEAT + c];
    *(uint4*)dst = *(uint4*)&o[0];
    *(uint4*)(dst + 8) = *(uint4*)&o[8];
  }
}

// ---------- pooling stage 1: VECTORIZED (uint4 = 8 bf16 per lane), 400 blocks x 100 rows ----------
__global__ __launch_bounds__(256) void pool_partial(const uint4* __restrict__ h2u,
                                                    float* __restrict__ partials) {
  int blk = blockIdx.x;
  int tid = threadIdx.x;
  int rg = tid >> 5, cl = tid & 31;
  int rend = blk * 100 + 100;
  float acc[8];
#pragma unroll
  for (int j = 0; j < 8; ++j) acc[j] = 0.0f;
  for (int r = blk * 100 + rg; r < rend; r += 8) {
    uint4 m = h2u[(size_t)r * 32 + cl];
    unsigned int mm[4] = {m.x, m.y, m.z, m.w};
#pragma unroll
    for (int j = 0; j < 4; ++j) {
      acc[2 * j + 0] += bf2f((unsigned short)(mm[j] & 0xffffu));
      acc[2 * j + 1] += bf2f((unsigned short)(mm[j] >> 16));
    }
  }
  __shared__ float red[8][256];
#pragma unroll
  for (int j = 0; j < 8; ++j) red[rg][cl * 8 + j] = acc[j];
  __syncthreads();
  float s = red[0][tid] + red[1][tid] + red[2][tid] + red[3][tid]
          + red[4][tid] + red[5][tid] + red[6][tid] + red[7][tid];
  partials[(size_t)blk * 256 + tid] = s;
}

// ---------- pooling stage 2 + FC (400 KB read, single block) ----------
__global__ __launch_bounds__(256) void pool_fc(const float* __restrict__ partials,
                                               const float* __restrict__ Wfc,
                                               const float* __restrict__ bfc,
                                               float* __restrict__ out) {
  __shared__ float pooled[BATCH][FEAT];
  int t = threadIdx.x;
  float s0 = 0.f, s1 = 0.f;
  for (int p = 0; p < PBLK2 / 2; ++p) {
    s0 += partials[(size_t)p * 256 + t];
    s1 += partials[(size_t)(PBLK2 / 2 + p) * 256 + t];
  }
  pooled[0][t] = s0 / (float)NNODES;
  pooled[1][t] = s1 / (float)NNODES;
  __syncthreads();
  if (t < BATCH * OOUT) {
    int b = t >> 6, o = t & 63;
    float acc = bfc[o];
    for (int c2 = 0; c2 < FEAT; ++c2)
      acc = fmaf(pooled[b][c2], Wfc[c2 * OOUT + o], acc);
    out[b * OOUT + o] = acc;
  }
}

extern "C" void kernel_launch(void* const* d_in, const int* in_sizes, int n_in,
                              void* d_out, int out_size, void* d_ws, size_t ws_size,
                              hipStream_t stream) {
  const float* x    = (const float*)d_in[0];
  const float* W1   = (const float*)d_in[1];
  const float* b1   = (const float*)d_in[2];
  const float* W2   = (const float*)d_in[3];
  const float* b2   = (const float*)d_in[4];
  const float* Wfc  = (const float*)d_in[5];
  const float* bfc  = (const float*)d_in[6];
  const int*   eraw = (const int*)d_in[7];
  int E = in_sizes[7] / 2;
  float* out = (float*)d_out;

  char* ws = (char*)d_ws;
  size_t off = 0;
  auto alloc = [&](size_t elems4B) -> void* {
    void* p = ws + off * 4;
    off += (elems4B + 3) & ~(size_t)3;
    return p;
  };
  int*   flag      = (int*)alloc(4);
  int*   cnt       = (int*)alloc(NNODES);
  float* dinv      = (float*)alloc(NNODES);
  int*   row_start = (int*)alloc(NNODES + 1);
  int*   fill      = (int*)alloc(NNODES);
  int*   chunkOff  = (int*)alloc(NCHUNK + 4);
  int*   csr_src   = (int*)alloc(E);
  float* csr_norm  = (float*)alloc(E);
  unsigned short* w1hi = (unsigned short*)alloc(65536 / 2);
  unsigned short* w1lo = (unsigned short*)alloc(65536 / 2);
  unsigned short* w2hi = (unsigned short*)alloc(65536 / 2);
  unsigned short* w2lo = (unsigned short*)alloc(65536 / 2);
  unsigned int*   h8   = (unsigned int*)alloc((size_t)H8ROWS * 64);
  unsigned short* a1   = (unsigned short*)alloc((size_t)MROWS * FEAT / 2);
  float* partials  = (float*)alloc((size_t)PBLK2 * 256);

  int eg = (E + 255) / 256;
  prep_kernel<<<512, 256, 0, stream>>>(W1, W2, w1hi, w1lo, w2hi, w2lo, eraw, E, flag,
                                       cnt, fill, chunkOff);
  count_kernel<<<eg, 256, 0, stream>>>(eraw, flag, cnt, E);
  scan_a_kernel<<<NCHUNK, 256, 0, stream>>>(cnt, row_start, dinv, chunkOff);
  scatter_kernel<<<eg, 256, 0, stream>>>(eraw, flag, row_start, chunkOff, fill, dinv,
                                         csr_src, csr_norm, E);

  gemm_mfma<1><<<640, 256, 0, stream>>>(x, w1hi, w1lo, h8);
  agg_kernel<<<NNODES, 128, 0, stream>>>((const uint4*)h8, row_start, chunkOff,
                                         csr_src, csr_norm, dinv, b1, a1);
  gemm_mfma<0><<<640, 256, 0, stream>>>(a1, w2hi, w2lo, h8);
  agg_kernel<<<NNODES, 128, 0, stream>>>((const uint4*)h8, row_start, chunkOff,
                                         csr_src, csr_norm, dinv, b2, a1);
  pool_partial<<<PBLK2, 256, 0, stream>>>((const uint4*)a1, partials);
  pool_fc<<<1, 256, 0, stream>>>(partials, Wfc, bfc, out);
}

// Round 17
// 176.379 us; speedup vs baseline: 1.7308x; 1.0391x over previous
//
#include <hip/hip_runtime.h>

#define NNODES 20000
#define BATCH  2
#define FEAT   256
#define OOUT   64
#define PBLK2  400        // pool stage-1 blocks (100 flattened rows each)
#define MROWS  40000
#define NPB    20096      // padded nodes per batch (157*128)
#define H8ROWS 40192      // 2*NPB interleaved rows (n*2+b)
#define NCHUNK 20

typedef short  bhalf8 __attribute__((ext_vector_type(8)));
typedef float  floatx4 __attribute__((ext_vector_type(4)));
typedef float  floatx2 __attribute__((ext_vector_type(2)));

__device__ __forceinline__ float bf2f(unsigned short u) {
  return __uint_as_float(((unsigned int)u) << 16);
}
__device__ __forceinline__ unsigned short f2bf(float f) {  // RNE
  unsigned int u = __float_as_uint(f);
  return (unsigned short)((u + 0x7fffu + ((u >> 16) & 1u)) >> 16);
}
__device__ __forceinline__ unsigned int pack4_fp8(float a, float b, float c, float d) {
  int p = __builtin_amdgcn_cvt_pk_fp8_f32(a, b, 0, false);
  p = __builtin_amdgcn_cvt_pk_fp8_f32(c, d, p, true);
  return (unsigned int)p;
}

// ---------- prep: zero cnt/fill/chunkOff + wprep (both W) + detect edge dtype; grid=512 ----------
__global__ __launch_bounds__(256) void prep_kernel(const float* __restrict__ W1,
                                                   const float* __restrict__ W2,
                                                   unsigned short* __restrict__ w1hi,
                                                   unsigned short* __restrict__ w1lo,
                                                   unsigned short* __restrict__ w2hi,
                                                   unsigned short* __restrict__ w2lo,
                                                   const int* __restrict__ raw, int E,
                                                   int* __restrict__ flag,
                                                   int* __restrict__ cnt,
                                                   int* __restrict__ fill,
                                                   int* __restrict__ chunkOff) {
  int bid = blockIdx.x, tid = threadIdx.x;
  int idx = bid * 256 + tid;                 // [0, 131072)
  int which = idx >> 16, loc = idx & 65535;
  const float* W = which ? W2 : W1;
  unsigned short* Whi = which ? w2hi : w1hi;
  unsigned short* Wlo = which ? w2lo : w1lo;
  int k = loc >> 8, n = loc & 255;
  float w = W[loc];
  unsigned short hi = f2bf(w);
  unsigned short lo = f2bf(w - bf2f(hi));
  int g = n >> 4, ln = n & 15;
  int ks = k >> 5, ch = (k >> 3) & 3, j = k & 7;
  int addr = ((ks * 16 + g) * 64 + ch * 16 + ln) * 8 + j;
  Whi[addr] = hi;
  Wlo[addr] = lo;
  if (idx < NNODES) { cnt[idx] = 0; fill[idx] = 0; }
  if (idx < NCHUNK) chunkOff[idx] = 0;
  if (bid == 511) {
    __shared__ int any;
    if (tid == 0) any = 0;
    __syncthreads();
    int nchk = E < 2048 ? E : 2048;
    for (int i = tid; i < nchk; i += 256)
      if (raw[2 * i + 1] != 0) any = 1;      // int64 high words are 0
    __syncthreads();
    if (tid == 0) *flag = any;               // 1 => int32 layout
  }
}

// ---------- degree count straight from eraw ----------
__global__ void count_kernel(const int* __restrict__ raw, const int* __restrict__ flag,
                             int* __restrict__ cnt, int E) {
  int e = blockIdx.x * blockDim.x + threadIdx.x;
  if (e >= E) return;
  int d = (*flag) ? raw[E + e] : raw[2 * (E + e)];
  atomicAdd(&cnt[d], 1);
}

// ---------- parallel scan: 20 blocks, local exclusive scan + dinv; chunk totals via int atomics ----------
__global__ __launch_bounds__(256) void scan_a_kernel(const int* __restrict__ cnt,
                                                     int* __restrict__ row_start,
                                                     float* __restrict__ dinv,
                                                     int* __restrict__ chunkOff) {
  int c = blockIdx.x, tid = threadIdx.x;
  int base = c * 1024 + tid * 4;
  int v[4]; int tsum = 0;
#pragma unroll
  for (int j = 0; j < 4; ++j) {
    v[j] = (base + j < NNODES) ? cnt[base + j] : 0;
    tsum += v[j];
  }
  int lane = tid & 63, wv = tid >> 6;
  int x = tsum;
#pragma unroll
  for (int off = 1; off < 64; off <<= 1) {
    int t = __shfl_up(x, off);
    if (lane >= off) x += t;
  }
  __shared__ int wsum[4];
  if (lane == 63) wsum[wv] = x;
  __syncthreads();
  int woff = 0;
  for (int w = 0; w < wv; ++w) woff += wsum[w];
  int run = woff + x - tsum;                 // exclusive prefix (local to chunk)
#pragma unroll
  for (int j = 0; j < 4; ++j) {
    if (base + j <= NNODES) row_start[base + j] = run;   // local-exclusive; global = +chunkOff
    if (base + j < NNODES) dinv[base + j] = 1.0f / sqrtf((float)(v[j] + 1));
    run += v[j];
  }
  if (tid == 0) {
    int T = wsum[0] + wsum[1] + wsum[2] + wsum[3];
    for (int c2 = c + 1; c2 < NCHUNK; ++c2) atomicAdd(&chunkOff[c2], T);  // int: exact, order-free
  }
}

// ---------- scatter straight from eraw ----------
__global__ void scatter_kernel(const int* __restrict__ raw, const int* __restrict__ flag,
                               const int* __restrict__ row_start, const int* __restrict__ chunkOff,
                               int* __restrict__ fill, const float* __restrict__ dinv,
                               int* __restrict__ csr_src, float* __restrict__ csr_norm, int E) {
  int e = blockIdx.x * blockDim.x + threadIdx.x;
  if (e >= E) return;
  int s, d;
  if (*flag) { s = raw[e];     d = raw[E + e]; }
  else       { s = raw[2 * e]; d = raw[2 * (E + e)]; }
  int p = row_start[d] + chunkOff[d >> 10] + atomicAdd(&fill[d], 1);
  csr_src[p] = s;
  csr_norm[p] = dinv[s] * dinv[d];
}

// ---------- MFMA GEMM: 32KiB dbuf LDS; XCD-paired swizzle (halves of a tile 8 bids apart) ----------
template <int AFP32>
__global__ __launch_bounds__(256) void gemm_mfma(const void* __restrict__ Av,
                                                 const unsigned short* __restrict__ Whi,
                                                 const unsigned short* __restrict__ Wlo,
                                                 unsigned int* __restrict__ C) {
  int bid = blockIdx.x;
  int tile = (bid >> 4) * 8 + (bid & 7);
  int half = (bid >> 3) & 1;
  if (tile >= 314) return;
  __shared__ unsigned short lds[2][8192];
  int b = tile >= 157 ? 1 : 0;
  int nbase = (tile - b * 157) * 128;
  int tid = threadIdx.x, lane = tid & 63, wv = tid >> 6;
  int kc = (lane >> 4) * 8;

  const float* Af          = (const float*)Av;
  const unsigned short* Ab = (const unsigned short*)Av;

  int nn[2], mr[2];
#pragma unroll
  for (int t = 0; t < 2; ++t) {
    int nl = nbase + wv * 32 + t * 16 + (lane & 15);
    nn[t] = nl;
    int ncl = nl > NNODES - 1 ? NNODES - 1 : nl;
    mr[t] = b * NNODES + ncl;
  }

  floatx4 acc[2][8];
#pragma unroll
  for (int t = 0; t < 2; ++t)
#pragma unroll
    for (int g = 0; g < 8; ++g) acc[t][g] = (floatx4)(0.0f);

  bhalf8 st[4];
  auto stage_load = [&](int ks) {
#pragma unroll
    for (int i2 = 0; i2 < 4; ++i2) {
      int u = i2 * 256 + tid;
      int hl = u >> 9, g = (u >> 6) & 7, l = u & 63;
      const unsigned short* Wp = hl ? Wlo : Whi;
      st[i2] = *(const bhalf8*)&Wp[((size_t)(ks * 16 + half * 8 + g) * 64 + l) * 8];
    }
  };
  auto stage_write = [&](int buf) {
#pragma unroll
    for (int i2 = 0; i2 < 4; ++i2) {
      int u = i2 * 256 + tid;
      *(bhalf8*)&lds[buf][(size_t)u * 8] = st[i2];
    }
  };
  auto load_a = [&](int ks, bhalf8 (&a)[2]) {
#pragma unroll
    for (int t = 0; t < 2; ++t) {
      if (AFP32) {
        const float* p = &Af[(size_t)mr[t] * FEAT + ks * 32 + kc];
        float4 u = *(const float4*)p;
        float4 v = *(const float4*)(p + 4);
        a[t][0] = (short)f2bf(u.x); a[t][1] = (short)f2bf(u.y);
        a[t][2] = (short)f2bf(u.z); a[t][3] = (short)f2bf(u.w);
        a[t][4] = (short)f2bf(v.x); a[t][5] = (short)f2bf(v.y);
        a[t][6] = (short)f2bf(v.z); a[t][7] = (short)f2bf(v.w);
      } else {
        a[t] = *(const bhalf8*)&Ab[(size_t)mr[t] * FEAT + ks * 32 + kc];
      }
    }
  };
  auto step = [&](int buf, bhalf8 (&a)[2]) {
#pragma unroll
    for (int g = 0; g < 8; ++g) {
      bhalf8 bh = *(const bhalf8*)&lds[buf][((size_t)g * 64 + lane) * 8];
      bhalf8 bl = *(const bhalf8*)&lds[buf][((size_t)(512 + g * 64) + lane) * 8];
#pragma unroll
      for (int t = 0; t < 2; ++t)
        acc[t][g] = __builtin_amdgcn_mfma_f32_16x16x32_bf16(bh, a[t], acc[t][g], 0, 0, 0);
#pragma unroll
      for (int t = 0; t < 2; ++t)
        acc[t][g] = __builtin_amdgcn_mfma_f32_16x16x32_bf16(bl, a[t], acc[t][g], 0, 0, 0);
    }
  };

  stage_load(0);
  stage_write(0);
  __syncthreads();
  bhalf8 aC[2];
  load_a(0, aC);
  int cur = 0;
#pragma unroll
  for (int ks = 0; ks < 8; ++ks) {
    bhalf8 aN[2];
    if (ks < 7) {
      stage_load(ks + 1);
      load_a(ks + 1, aN);
    }
    step(cur, aC);
    if (ks < 7) {
      stage_write(cur ^ 1);
      __syncthreads();
      aC[0] = aN[0]; aC[1] = aN[1];
    }
    cur ^= 1;
  }

  int nc = (lane >> 4) * 4;
#pragma unroll
  for (int t = 0; t < 2; ++t) {
    size_t r = (size_t)nn[t] * 2 + b;
#pragma unroll
    for (int g = 0; g < 8; ++g) {
      int col = (half * 8 + g) * 16 + nc;
      C[r * 64 + (col >> 2)] =
          pack4_fp8(acc[t][g][0], acc[t][g][1], acc[t][g][2], acc[t][g][3]);
    }
  }
}

// ---------- aggregation: one node per block; h8 rows are 512B (n*2+b interleaved) ----------
// 128 thr: slot q = (wave<<1)|(lane>>5) handles edges (i-s0)%4==q; cl = lane&31 spans the
// 512B row (cl<16: batch0 feats, cl>=16: batch1). Combine: shfl_xor(32) + LDS cross-wave.
__global__ __launch_bounds__(128) void agg_kernel(const uint4* __restrict__ h8,
                                                  const int* __restrict__ row_start,
                                                  const int* __restrict__ chunkOff,
                                                  const int* __restrict__ csr_src,
                                                  const float* __restrict__ csr_norm,
                                                  const float* __restrict__ dinv,
                                                  const float* __restrict__ bias,
                                                  unsigned short* __restrict__ out) {
  int n = blockIdx.x;
  int tid = threadIdx.x;
  int wave = tid >> 6, lane = tid & 63;
  int q = (wave << 1) | (lane >> 5);   // edge slot 0..3
  int cl = lane & 31;                  // uint4 index within 512B row

  float a[16];
#pragma unroll
  for (int j = 0; j < 16; ++j) a[j] = 0.0f;

  auto dec_fma = [&](uint4 m, float w) {
    unsigned int mm[4] = {m.x, m.y, m.z, m.w};
#pragma unroll
    for (int j = 0; j < 4; ++j) {
      floatx2 lo = __builtin_amdgcn_cvt_pk_f32_fp8((int)mm[j], false);
      floatx2 hi = __builtin_amdgcn_cvt_pk_f32_fp8((int)mm[j], true);
      a[j * 4 + 0] = fmaf(w, lo[0], a[j * 4 + 0]);
      a[j * 4 + 1] = fmaf(w, lo[1], a[j * 4 + 1]);
      a[j * 4 + 2] = fmaf(w, hi[0], a[j * 4 + 2]);
      a[j * 4 + 3] = fmaf(w, hi[1], a[j * 4 + 3]);
    }
  };

  float di = dinv[n];
  if (q == 0) dec_fma(h8[(size_t)n * 32 + cl], di * di);   // self term, both batches

  int s0 = row_start[n] + chunkOff[n >> 10];
  int s1 = row_start[n + 1] + chunkOff[(n + 1) >> 10];
  int i = s0 + q;
  for (; i + 4 < s1; i += 8) {          // 2 edges/slot-iter -> 8 x 512B gathers in flight
    int sa = csr_src[i], sb = csr_src[i + 4];
    float wa = csr_norm[i], wb = csr_norm[i + 4];
    uint4 ma = h8[(size_t)sa * 32 + cl];
    uint4 mb = h8[(size_t)sb * 32 + cl];
    dec_fma(ma, wa);
    dec_fma(mb, wb);
  }
  if (i < s1) dec_fma(h8[(size_t)csr_src[i] * 32 + cl], csr_norm[i]);

  // combine slot pairs within each wave
#pragma unroll
  for (int j = 0; j < 16; ++j) a[j] += __shfl_xor(a[j], 32);

  // cross-wave combine via LDS (padded stride 17: conflict-free)
  __shared__ float red[32][17];
  if (wave == 1 && lane < 32) {
#pragma unroll
    for (int j = 0; j < 16; ++j) red[lane][j] = a[j];
  }
  __syncthreads();
  if (wave == 0 && lane < 32) {
    int b = cl >> 4;                    // batch
    int c = (cl & 15) * 16;             // feature base
#pragma unroll
    for (int j = 0; j < 16; ++j) a[j] += red[lane][j];
    unsigned short o[16];
#pragma unroll
    for (int j = 0; j < 16; ++j)
      o[j] = f2bf(fmaxf(a[j] + bias[c + j], 0.0f));
    unsigned short* dst = &out[((size_t)b * NNODES + n) * FEAT + c];
    *(uint4*)dst = *(uint4*)&o[0];
    *(uint4*)(dst + 8) = *(uint4*)&o[8];
  }
}

// ---------- pooling stage 1: VECTORIZED (uint4 = 8 bf16 per lane), 400 blocks x 100 rows ----------
__global__ __launch_bounds__(256) void pool_partial(const uint4* __restrict__ h2u,
                                                    float* __restrict__ partials) {
  int blk = blockIdx.x;
  int tid = threadIdx.x;
  int rg = tid >> 5, cl = tid & 31;
  int rend = blk * 100 + 100;
  float acc[8];
#pragma unroll
  for (int j = 0; j < 8; ++j) acc[j] = 0.0f;
  for (int r = blk * 100 + rg; r < rend; r += 8) {
    uint4 m = h2u[(size_t)r * 32 + cl];
    unsigned int mm[4] = {m.x, m.y, m.z, m.w};
#pragma unroll
    for (int j = 0; j < 4; ++j) {
      acc[2 * j + 0] += bf2f((unsigned short)(mm[j] & 0xffffu));
      acc[2 * j + 1] += bf2f((unsigned short)(mm[j] >> 16));
    }
  }
  __shared__ float red[8][256];
#pragma unroll
  for (int j = 0; j < 8; ++j) red[rg][cl * 8 + j] = acc[j];
  __syncthreads();
  float s = red[0][tid] + red[1][tid] + red[2][tid] + red[3][tid]
          + red[4][tid] + red[5][tid] + red[6][tid] + red[7][tid];
  partials[(size_t)blk * 256 + tid] = s;
}

// ---------- pooling stage 2 + FC (400 KB read, single block) ----------
__global__ __launch_bounds__(256) void pool_fc(const float* __restrict__ partials,
                                               const float* __restrict__ Wfc,
                                               const float* __restrict__ bfc,
                                               float* __restrict__ out) {
  __shared__ float pooled[BATCH][FEAT];
  int t = threadIdx.x;
  float s0 = 0.f, s1 = 0.f;
  for (int p = 0; p < PBLK2 / 2; ++p) {
    s0 += partials[(size_t)p * 256 + t];
    s1 += partials[(size_t)(PBLK2 / 2 + p) * 256 + t];
  }
  pooled[0][t] = s0 / (float)NNODES;
  pooled[1][t] = s1 / (float)NNODES;
  __syncthreads();
  if (t < BATCH * OOUT) {
    int b = t >> 6, o = t & 63;
    float acc = bfc[o];
    for (int c2 = 0; c2 < FEAT; ++c2)
      acc = fmaf(pooled[b][c2], Wfc[c2 * OOUT + o], acc);
    out[b * OOUT + o] = acc;
  }
}

extern "C" void kernel_launch(void* const* d_in, const int* in_sizes, int n_in,
                              void* d_out, int out_size, void* d_ws, size_t ws_size,
                              hipStream_t stream) {
  const float* x    = (const float*)d_in[0];
  const float* W1   = (const float*)d_in[1];
  const float* b1   = (const float*)d_in[2];
  const float* W2   = (const float*)d_in[3];
  const float* b2   = (const float*)d_in[4];
  const float* Wfc  = (const float*)d_in[5];
  const float* bfc  = (const float*)d_in[6];
  const int*   eraw = (const int*)d_in[7];
  int E = in_sizes[7] / 2;
  float* out = (float*)d_out;

  char* ws = (char*)d_ws;
  size_t off = 0;
  auto alloc = [&](size_t elems4B) -> void* {
    void* p = ws + off * 4;
    off += (elems4B + 3) & ~(size_t)3;
    return p;
  };
  int*   flag      = (int*)alloc(4);
  int*   cnt       = (int*)alloc(NNODES);
  float* dinv      = (float*)alloc(NNODES);
  int*   row_start = (int*)alloc(NNODES + 1);
  int*   fill      = (int*)alloc(NNODES);
  int*   chunkOff  = (int*)alloc(NCHUNK + 4);
  int*   csr_src   = (int*)alloc(E);
  float* csr_norm  = (float*)alloc(E);
  unsigned short* w1hi = (unsigned short*)alloc(65536 / 2);
  unsigned short* w1lo = (unsigned short*)alloc(65536 / 2);
  unsigned short* w2hi = (unsigned short*)alloc(65536 / 2);
  unsigned short* w2lo = (unsigned short*)alloc(65536 / 2);
  unsigned int*   h8   = (unsigned int*)alloc((size_t)H8ROWS * 64);
  unsigned short* a1   = (unsigned short*)alloc((size_t)MROWS * FEAT / 2);
  float* partials  = (float*)alloc((size_t)PBLK2 * 256);

  int eg = (E + 255) / 256;
  prep_kernel<<<512, 256, 0, stream>>>(W1, W2, w1hi, w1lo, w2hi, w2lo, eraw, E, flag,
                                       cnt, fill, chunkOff);
  count_kernel<<<eg, 256, 0, stream>>>(eraw, flag, cnt, E);
  scan_a_kernel<<<NCHUNK, 256, 0, stream>>>(cnt, row_start, dinv, chunkOff);
  scatter_kernel<<<eg, 256, 0, stream>>>(eraw, flag, row_start, chunkOff, fill, dinv,
                                         csr_src, csr_norm, E);

  gemm_mfma<1><<<640, 256, 0, stream>>>(x, w1hi, w1lo, h8);
  agg_kernel<<<NNODES, 128, 0, stream>>>((const uint4*)h8, row_start, chunkOff,
                                         csr_src, csr_norm, dinv, b1, a1);
  gemm_mfma<0><<<640, 256, 0, stream>>>(a1, w2hi, w2lo, h8);
  agg_kernel<<<NNODES, 128, 0, stream>>>((const uint4*)h8, row_start, chunkOff,
                                         csr_src, csr_norm, dinv, b2, a1);
  pool_partial<<<PBLK2, 256, 0, stream>>>((const uint4*)a1, partials);
  pool_fc<<<1, 256, 0, stream>>>(partials, Wfc, bfc, out);
}